// Round 12
// baseline (40.389 us; speedup 1.0000x reference)
//
#include <hip/hip_runtime.h>

#define NN 1024

// ---------- K1: first linear + neighbor-list build (A read ONCE) ----------
// 256 blocks x 512 threads, 4 nodes/block. (unchanged from R11)
__global__ __launch_bounds__(512) void lin_build(
    const float* __restrict__ X, const float* __restrict__ Wp,
    const float* __restrict__ bp, const float* __restrict__ Ws,
    const float* __restrict__ bs, const int* __restrict__ A,
    float* __restrict__ pooled, float* __restrict__ sbuf,
    int* __restrict__ nbrG, int* __restrict__ cntG)
{
    __shared__ float xL[4][128];
    __shared__ float lp[2][4][192];
    __shared__ unsigned long long masksL[4][16];
    __shared__ int pfxL[4][16];

    const int tid  = threadIdx.x;
    const int lane = tid & 63;
    const int wv   = tid >> 6;       // wave 0..7
    const int v0   = blockIdx.x * 4;

    xL[tid >> 7][tid & 127] = X[v0 * 128 + tid];
    __syncthreads();

    if (tid < 384) {  // GEMV partials: 192 outputs x 2 k-halves, 4 rows/thread
        const int kh = (tid >= 192) ? 1 : 0;
        const int j = tid - kh * 192;
        const float* w; int ld;
        if (j < 128) { w = Wp + j;         ld = 128; }
        else         { w = Ws + (j - 128); ld = 64;  }
        const int k0 = kh * 64;
        float a0 = 0.f, a1 = 0.f, a2 = 0.f, a3 = 0.f;
        #pragma unroll 4
        for (int k = 0; k < 64; ++k) {
            const float wvv = w[(k0 + k) * ld];
            a0 += xL[0][k0 + k] * wvv;  a1 += xL[1][k0 + k] * wvv;
            a2 += xL[2][k0 + k] * wvv;  a3 += xL[3][k0 + k] * wvv;
        }
        lp[kh][0][j] = a0; lp[kh][1][j] = a1; lp[kh][2][j] = a2; lp[kh][3][j] = a3;
    }
    {   // A-scan: wave wv -> row (wv>>1), chunks (wv&1)*8..+8
        const int r = wv >> 1;
        const int* Arow = A + (v0 + r) * NN;
        #pragma unroll
        for (int c8 = 0; c8 < 8; ++c8) {
            const int c = (wv & 1) * 8 + c8;
            const unsigned long long m = __ballot(Arow[c * 64 + lane] != 0);
            if (lane == 0) masksL[r][c] = m;
        }
    }
    __syncthreads();

    if (tid < 4) {
        int off = 0;
        #pragma unroll
        for (int c = 0; c < 16; ++c) {
            pfxL[tid][c] = off;
            off += __popcll(masksL[tid][c]);
        }
        cntG[v0 + tid] = off;
    }
    if (tid < 192) {
        #pragma unroll
        for (int r = 0; r < 4; ++r) {
            const float t = lp[0][r][tid] + lp[1][r][tid];
            if (tid < 128) pooled[(v0 + r) * 128 + tid] = fmaxf(t + bp[tid], 0.f);
            else           sbuf[(v0 + r) * 64 + (tid - 128)] = t + bs[tid - 128];
        }
    }
    __syncthreads();

    {   // compaction scatter
        const int r = wv >> 1;
        #pragma unroll
        for (int c8 = 0; c8 < 8; ++c8) {
            const int c = (wv & 1) * 8 + c8;
            const unsigned long long m = masksL[r][c];
            if ((m >> lane) & 1ull) {
                const int pos = pfxL[r][c] + __popcll(m & ((1ull << lane) - 1ull));
                nbrG[(v0 + r) * NN + pos] = c * 64 + lane;
            }
        }
    }
}

// ---------- K2/K3: SINGLE-WAVE blocks, 2 nodes per wave, zero barrier cost ----
// 512 blocks x 64 threads. Every __syncthreads() in a 1-wave workgroup compiles
// to a waitcnt (no inter-wave convergence) -> the phase chain is pure dataflow.
// Lane l owns dims {2l, 2l+1} in the gather; weights shared across both nodes.
// MODE 0: writes pooled2 = relu(h@Wp2+bp2), s2 = h@Ws2+bs2
// MODE 1: Wp2:=Wh(unused), writes outh = h@Wh+bh
template <int MODE>
__global__ __launch_bounds__(64) void wave_agg(
    const int* __restrict__ nbrG, const int* __restrict__ cntG,
    const float* __restrict__ pooled, const float* __restrict__ sbuf,
    const float* __restrict__ Wn, const float* __restrict__ bn,
    const float* __restrict__ Wp2, const float* __restrict__ bp2,
    const float* __restrict__ Ws2, const float* __restrict__ bs2,
    float* __restrict__ out_pooled, float* __restrict__ out_s,
    const float* __restrict__ Wh, const float* __restrict__ bh,
    float* __restrict__ outh)
{
    __shared__ int   nbrL[2][256];
    __shared__ float aggL[2][128];
    __shared__ float hLL[2][128];

    const int v0   = blockIdx.x * 2;
    const int lane = threadIdx.x;

    const int n0 = cntG[v0];
    const int n1 = cntG[v0 + 1];
    const float sv0 = sbuf[v0 * 64 + lane];
    const float sv1 = sbuf[(v0 + 1) * 64 + lane];

    // coalesced neighbor-list preload (LDS cap 256; global fallback beyond)
    for (int i = lane; i < n0 && i < 256; i += 64) nbrL[0][i] = nbrG[v0 * NN + i];
    for (int i = lane; i < n1 && i < 256; i += 64) nbrL[1][i] = nbrG[(v0 + 1) * NN + i];
    __syncthreads();

    // gather-max per node: 8 independent float2 loads in flight
    #pragma unroll
    for (int r = 0; r < 2; ++r) {
        const int n  = r ? n1 : n0;
        const int nl = n < 256 ? n : 256;
        const float* base = pooled + 2 * lane;
        float2 m0 = {-1e30f, -1e30f}, m1 = m0, m2 = m0, m3 = m0;
        float2 m4 = m0, m5 = m0, m6 = m0, m7 = m0;
        int p = 0;
        for (; p + 7 < nl; p += 8) {
            const float2 t0 = *(const float2*)&base[nbrL[r][p + 0] * 128];
            const float2 t1 = *(const float2*)&base[nbrL[r][p + 1] * 128];
            const float2 t2 = *(const float2*)&base[nbrL[r][p + 2] * 128];
            const float2 t3 = *(const float2*)&base[nbrL[r][p + 3] * 128];
            const float2 t4 = *(const float2*)&base[nbrL[r][p + 4] * 128];
            const float2 t5 = *(const float2*)&base[nbrL[r][p + 5] * 128];
            const float2 t6 = *(const float2*)&base[nbrL[r][p + 6] * 128];
            const float2 t7 = *(const float2*)&base[nbrL[r][p + 7] * 128];
            m0.x = fmaxf(m0.x, t0.x); m0.y = fmaxf(m0.y, t0.y);
            m1.x = fmaxf(m1.x, t1.x); m1.y = fmaxf(m1.y, t1.y);
            m2.x = fmaxf(m2.x, t2.x); m2.y = fmaxf(m2.y, t2.y);
            m3.x = fmaxf(m3.x, t3.x); m3.y = fmaxf(m3.y, t3.y);
            m4.x = fmaxf(m4.x, t4.x); m4.y = fmaxf(m4.y, t4.y);
            m5.x = fmaxf(m5.x, t5.x); m5.y = fmaxf(m5.y, t5.y);
            m6.x = fmaxf(m6.x, t6.x); m6.y = fmaxf(m6.y, t6.y);
            m7.x = fmaxf(m7.x, t7.x); m7.y = fmaxf(m7.y, t7.y);
        }
        for (; p < nl; ++p) {
            const float2 t = *(const float2*)&base[nbrL[r][p] * 128];
            m0.x = fmaxf(m0.x, t.x); m0.y = fmaxf(m0.y, t.y);
        }
        for (; p < n; ++p) {  // ultra-rare spill path (n > 256)
            const float2 t = *(const float2*)&base[nbrG[(v0 + r) * NN + p] * 128];
            m0.x = fmaxf(m0.x, t.x); m0.y = fmaxf(m0.y, t.y);
        }
        m0.x = fmaxf(fmaxf(m0.x, m1.x), fmaxf(m2.x, m3.x));
        m0.y = fmaxf(fmaxf(m0.y, m1.y), fmaxf(m2.y, m3.y));
        m4.x = fmaxf(fmaxf(m4.x, m5.x), fmaxf(m6.x, m7.x));
        m4.y = fmaxf(fmaxf(m4.y, m5.y), fmaxf(m6.y, m7.y));
        m0.x = fmaxf(m0.x, m4.x);
        m0.y = fmaxf(m0.y, m4.y);
        aggL[r][2 * lane]     = (m0.x <= -5e29f) ? 0.f : m0.x;  // isolated -> 0
        aggL[r][2 * lane + 1] = (m0.y <= -5e29f) ? 0.f : m0.y;
    }
    __syncthreads();

    // agg @ Wn: lane = output j, both nodes share the weight stream
    float wa0 = 0.f, wa1 = 0.f;
    #pragma unroll 4
    for (int k4 = 0; k4 < 128; k4 += 4) {
        const float4 g0 = *(const float4*)&aggL[0][k4];
        const float4 g1 = *(const float4*)&aggL[1][k4];
        const float w0 = Wn[(k4 + 0) * 64 + lane];
        const float w1 = Wn[(k4 + 1) * 64 + lane];
        const float w2 = Wn[(k4 + 2) * 64 + lane];
        const float w3 = Wn[(k4 + 3) * 64 + lane];
        wa0 += g0.x * w0 + g0.y * w1 + g0.z * w2 + g0.w * w3;
        wa1 += g1.x * w0 + g1.y * w1 + g1.z * w2 + g1.w * w3;
    }

    // concat + relu + L2 norm (lane j holds dims j and 64+j of h)
    const float bnj = bn[lane];
    const float vs0 = fmaxf(sv0, 0.f), vw0 = fmaxf(wa0 + bnj, 0.f);
    const float vs1 = fmaxf(sv1, 0.f), vw1 = fmaxf(wa1 + bnj, 0.f);
    float ss0 = vs0 * vs0 + vw0 * vw0;
    float ss1 = vs1 * vs1 + vw1 * vw1;
    #pragma unroll
    for (int off = 32; off >= 1; off >>= 1) {
        ss0 += __shfl_xor(ss0, off, 64);
        ss1 += __shfl_xor(ss1, off, 64);
    }
    const float nr0 = fmaxf(sqrtf(ss0), 1e-12f);
    const float nr1 = fmaxf(sqrtf(ss1), 1e-12f);
    hLL[0][lane] = vs0 / nr0;  hLL[0][64 + lane] = vw0 / nr0;
    hLL[1][lane] = vs1 / nr1;  hLL[1][64 + lane] = vw1 / nr1;
    __syncthreads();

    if (MODE == 0) {
        // next-layer linears: lane does pooled2 dims {j, 64+j} + s2 dim j,
        // both nodes per thread (6 accumulator chains, 3 weight streams)
        float pa0 = 0.f, pb0 = 0.f, sa0 = 0.f;
        float pa1 = 0.f, pb1 = 0.f, sa1 = 0.f;
        #pragma unroll 4
        for (int k4 = 0; k4 < 128; k4 += 4) {
            const float4 h0 = *(const float4*)&hLL[0][k4];
            const float4 h1 = *(const float4*)&hLL[1][k4];
            #pragma unroll
            for (int kk = 0; kk < 4; ++kk) {
                const int k = k4 + kk;
                const float h0k = kk == 0 ? h0.x : kk == 1 ? h0.y : kk == 2 ? h0.z : h0.w;
                const float h1k = kk == 0 ? h1.x : kk == 1 ? h1.y : kk == 2 ? h1.z : h1.w;
                const float wpa = Wp2[k * 128 + lane];
                const float wpb = Wp2[k * 128 + 64 + lane];
                const float wss = Ws2[k * 64 + lane];
                pa0 += h0k * wpa;  pb0 += h0k * wpb;  sa0 += h0k * wss;
                pa1 += h1k * wpa;  pb1 += h1k * wpb;  sa1 += h1k * wss;
            }
        }
        const float bpa = bp2[lane], bpb = bp2[64 + lane], bss = bs2[lane];
        out_pooled[v0 * 128 + lane]            = fmaxf(pa0 + bpa, 0.f);
        out_pooled[v0 * 128 + 64 + lane]       = fmaxf(pb0 + bpb, 0.f);
        out_pooled[(v0 + 1) * 128 + lane]      = fmaxf(pa1 + bpa, 0.f);
        out_pooled[(v0 + 1) * 128 + 64 + lane] = fmaxf(pb1 + bpb, 0.f);
        out_s[v0 * 64 + lane]       = sa0 + bss;
        out_s[(v0 + 1) * 64 + lane] = sa1 + bss;
    } else {
        // classifier head: lanes 0..39, one output each, both nodes
        if (lane < 40) {
            float a0 = 0.f, a1 = 0.f;
            #pragma unroll 4
            for (int k4 = 0; k4 < 128; k4 += 4) {
                const float4 h0 = *(const float4*)&hLL[0][k4];
                const float4 h1 = *(const float4*)&hLL[1][k4];
                const float w0 = Wh[(k4 + 0) * 40 + lane];
                const float w1 = Wh[(k4 + 1) * 40 + lane];
                const float w2 = Wh[(k4 + 2) * 40 + lane];
                const float w3 = Wh[(k4 + 3) * 40 + lane];
                a0 += h0.x * w0 + h0.y * w1 + h0.z * w2 + h0.w * w3;
                a1 += h1.x * w0 + h1.y * w1 + h1.z * w2 + h1.w * w3;
            }
            const float b = bh[lane];
            outh[v0 * 40 + lane]       = b + a0;
            outh[(v0 + 1) * 40 + lane] = b + a1;
        }
    }
}

extern "C" void kernel_launch(void* const* d_in, const int* in_sizes, int n_in,
                              void* d_out, int out_size, void* d_ws, size_t ws_size,
                              hipStream_t stream) {
    const float* x   = (const float*)d_in[0];
    const int*   A   = (const int*)  d_in[1];
    const float* Wp1 = (const float*)d_in[2];
    const float* bp1 = (const float*)d_in[3];
    const float* Ws1 = (const float*)d_in[4];
    const float* bs1 = (const float*)d_in[5];
    const float* Wn1 = (const float*)d_in[6];
    const float* bn1 = (const float*)d_in[7];
    const float* Wp2 = (const float*)d_in[8];
    const float* bp2 = (const float*)d_in[9];
    const float* Ws2 = (const float*)d_in[10];
    const float* bs2 = (const float*)d_in[11];
    const float* Wn2 = (const float*)d_in[12];
    const float* bn2 = (const float*)d_in[13];
    const float* Wh  = (const float*)d_in[14];
    const float* bh  = (const float*)d_in[15];
    float* out = (float*)d_out;

    char* ws = (char*)d_ws;
    float* pooled1 = (float*)(ws);                  // 512 KB
    float* s1      = (float*)(ws + (512u << 10));   // 256 KB
    float* pooled2 = (float*)(ws + (768u << 10));   // 512 KB
    float* s2      = (float*)(ws + (1280u << 10));  // 256 KB
    int*   nbrG    = (int*)  (ws + (1536u << 10));  // 4 MB
    int*   cntG    = (int*)  (ws + (5632u << 10));  // 4 KB

    lin_build<<<NN / 4, 512, 0, stream>>>(x, Wp1, bp1, Ws1, bs1, A,
                                          pooled1, s1, nbrG, cntG);
    wave_agg<0><<<NN / 2, 64, 0, stream>>>(nbrG, cntG, pooled1, s1, Wn1, bn1,
                                           Wp2, bp2, Ws2, bs2,
                                           pooled2, s2, nullptr, nullptr, nullptr);
    wave_agg<1><<<NN / 2, 64, 0, stream>>>(nbrG, cntG, pooled2, s2, Wn2, bn2,
                                           nullptr, nullptr, nullptr, nullptr,
                                           nullptr, nullptr, Wh, bh, out);
}

// Round 14
// 31.703 us; speedup vs baseline: 1.2740x; 1.2740x over previous
//
#include <hip/hip_runtime.h>

#define NN 1024

// ---------- K1: first linear + neighbor-list build (A read ONCE) ----------
// 256 blocks x 512 threads, 4 nodes/block. (unchanged)
__global__ __launch_bounds__(512) void lin_build(
    const float* __restrict__ X, const float* __restrict__ Wp,
    const float* __restrict__ bp, const float* __restrict__ Ws,
    const float* __restrict__ bs, const int* __restrict__ A,
    float* __restrict__ pooled, float* __restrict__ sbuf,
    int* __restrict__ nbrG, int* __restrict__ cntG)
{
    __shared__ float xL[4][128];
    __shared__ float lp[2][4][192];
    __shared__ unsigned long long masksL[4][16];
    __shared__ int pfxL[4][16];

    const int tid  = threadIdx.x;
    const int lane = tid & 63;
    const int wv   = tid >> 6;       // wave 0..7
    const int v0   = blockIdx.x * 4;

    xL[tid >> 7][tid & 127] = X[v0 * 128 + tid];
    __syncthreads();

    if (tid < 384) {  // GEMV partials: 192 outputs x 2 k-halves, 4 rows/thread
        const int kh = (tid >= 192) ? 1 : 0;
        const int j = tid - kh * 192;
        const float* w; int ld;
        if (j < 128) { w = Wp + j;         ld = 128; }
        else         { w = Ws + (j - 128); ld = 64;  }
        const int k0 = kh * 64;
        float a0 = 0.f, a1 = 0.f, a2 = 0.f, a3 = 0.f;
        #pragma unroll 4
        for (int k = 0; k < 64; ++k) {
            const float wvv = w[(k0 + k) * ld];
            a0 += xL[0][k0 + k] * wvv;  a1 += xL[1][k0 + k] * wvv;
            a2 += xL[2][k0 + k] * wvv;  a3 += xL[3][k0 + k] * wvv;
        }
        lp[kh][0][j] = a0; lp[kh][1][j] = a1; lp[kh][2][j] = a2; lp[kh][3][j] = a3;
    }
    {   // A-scan: wave wv -> row (wv>>1), chunks (wv&1)*8..+8
        const int r = wv >> 1;
        const int* Arow = A + (v0 + r) * NN;
        #pragma unroll
        for (int c8 = 0; c8 < 8; ++c8) {
            const int c = (wv & 1) * 8 + c8;
            const unsigned long long m = __ballot(Arow[c * 64 + lane] != 0);
            if (lane == 0) masksL[r][c] = m;
        }
    }
    __syncthreads();

    if (tid < 4) {
        int off = 0;
        #pragma unroll
        for (int c = 0; c < 16; ++c) {
            pfxL[tid][c] = off;
            off += __popcll(masksL[tid][c]);
        }
        cntG[v0 + tid] = off;
    }
    if (tid < 192) {
        #pragma unroll
        for (int r = 0; r < 4; ++r) {
            const float t = lp[0][r][tid] + lp[1][r][tid];
            if (tid < 128) pooled[(v0 + r) * 128 + tid] = fmaxf(t + bp[tid], 0.f);
            else           sbuf[(v0 + r) * 64 + (tid - 128)] = t + bs[tid - 128];
        }
    }
    __syncthreads();

    {   // compaction scatter
        const int r = wv >> 1;
        #pragma unroll
        for (int c8 = 0; c8 < 8; ++c8) {
            const int c = (wv & 1) * 8 + c8;
            const unsigned long long m = masksL[r][c];
            if ((m >> lane) & 1ull) {
                const int pos = pfxL[r][c] + __popcll(m & ((1ull << lane) - 1ull));
                nbrG[(v0 + r) * NN + pos] = c * 64 + lane;
            }
        }
    }
}

// ---------- K2/K3: 256-thread / 4-wave blocks, ONE node per block ----------
// 1024 blocks -> 8 blocks/CU resident (32 waves/CU, max TLP); 5 barriers of
// 4-wave convergence each; neighbor indices read directly from global
// (identical addresses across lanes -> L1 broadcast; no LDS staging phase).
// MODE 0: writes out_pooled = relu(h@Wp2+bp2), out_s = h@Ws2+bs2
// MODE 1: writes outh = h@Wh+bh
template <int MODE>
__global__ __launch_bounds__(256) void agg_kernel(
    const int* __restrict__ nbrG, const int* __restrict__ cntG,
    const float* __restrict__ pooled, const float* __restrict__ sbuf,
    const float* __restrict__ Wn, const float* __restrict__ bn,
    const float* __restrict__ Wp2, const float* __restrict__ bp2,
    const float* __restrict__ Ws2, const float* __restrict__ bs2,
    float* __restrict__ out_pooled, float* __restrict__ out_s,
    const float* __restrict__ Wh, const float* __restrict__ bh,
    float* __restrict__ outh)
{
    __shared__ float part[2][128];
    __shared__ float aggL[128];
    __shared__ float wq[4][64];
    __shared__ float hL[128];
    __shared__ float red[2];

    const int v    = blockIdx.x;
    const int tid  = threadIdx.x;
    const int d    = tid & 127;
    const int half = tid >> 7;

    const int n = cntG[v];
    const int* __restrict__ nb = nbrG + v * NN;
    const float sv = (tid < 64) ? sbuf[v * 64 + tid] : 0.f;  // early self-row load

    // gather-max: team=half, stride 2, 8 independent loads in flight
    {
        float a0=-1e30f,a1=-1e30f,a2=-1e30f,a3=-1e30f,
              a4=-1e30f,a5=-1e30f,a6=-1e30f,a7=-1e30f;
        int p = half;
        for (; p + 14 < n; p += 16) {
            const int i0 = nb[p],      i1 = nb[p + 2],  i2 = nb[p + 4],  i3 = nb[p + 6];
            const int i4 = nb[p + 8],  i5 = nb[p + 10], i6 = nb[p + 12], i7 = nb[p + 14];
            a0 = fmaxf(a0, pooled[i0 * 128 + d]);
            a1 = fmaxf(a1, pooled[i1 * 128 + d]);
            a2 = fmaxf(a2, pooled[i2 * 128 + d]);
            a3 = fmaxf(a3, pooled[i3 * 128 + d]);
            a4 = fmaxf(a4, pooled[i4 * 128 + d]);
            a5 = fmaxf(a5, pooled[i5 * 128 + d]);
            a6 = fmaxf(a6, pooled[i6 * 128 + d]);
            a7 = fmaxf(a7, pooled[i7 * 128 + d]);
        }
        for (; p < n; p += 2) a0 = fmaxf(a0, pooled[nb[p] * 128 + d]);
        a0 = fmaxf(fmaxf(a0, a1), fmaxf(a2, a3));
        a4 = fmaxf(fmaxf(a4, a5), fmaxf(a6, a7));
        part[half][d] = fmaxf(a0, a4);
    }
    __syncthreads();                                   // b1
    if (half == 0) {
        const float m = fmaxf(part[0][d], part[1][d]);
        aggL[d] = (m <= -5e29f) ? 0.f : m;             // isolated -> 0
    }
    __syncthreads();                                   // b2

    // agg @ Wn: ksplit-4 x 64 outputs = 256 threads, 32 FMAs each
    {
        const int j = tid & 63, kh = tid >> 6, k0 = kh * 32;
        float a = 0.f;
        #pragma unroll 8
        for (int k = 0; k < 32; ++k) a += aggL[k0 + k] * Wn[(k0 + k) * 64 + j];
        wq[kh][j] = a;
    }
    __syncthreads();                                   // b3

    // concat + relu + L2 norm (threads 0..127, 2 waves)
    float val = 0.f;
    if (tid < 128) {
        val = (d < 64) ? sv
                       : (bn[d - 64] + wq[0][d - 64] + wq[1][d - 64]
                                     + wq[2][d - 64] + wq[3][d - 64]);
        val = fmaxf(val, 0.f);
        float ss = val * val;
        #pragma unroll
        for (int off = 32; off >= 1; off >>= 1) ss += __shfl_xor(ss, off, 64);
        if ((tid & 63) == 0) red[tid >> 6] = ss;
    }
    __syncthreads();                                   // b4
    if (tid < 128) {
        const float nrm = fmaxf(sqrtf(red[0] + red[1]), 1e-12f);
        hL[tid] = val / nrm;
    }
    __syncthreads();                                   // b5

    if (MODE == 0) {
        // next-layer linears: 192 threads, full-k (unroll-4 keeps 4 loads in flight)
        if (tid < 192) {
            const float* w; int ld;
            if (tid < 128) { w = Wp2 + tid;         ld = 128; }
            else           { w = Ws2 + (tid - 128); ld = 64;  }
            float a = 0.f;
            #pragma unroll 4
            for (int k = 0; k < 128; ++k) a += hL[k] * w[k * ld];
            if (tid < 128) out_pooled[v * 128 + tid] = fmaxf(a + bp2[tid], 0.f);
            else           out_s[v * 64 + (tid - 128)] = a + bs2[tid - 128];
        }
    } else {
        // head: ksplit-4 x 40 outputs = 160 threads
        if (tid < 160) {
            const int t = tid / 40, j = tid - t * 40, k0 = t * 32;
            float a = 0.f;
            #pragma unroll 8
            for (int k = 0; k < 32; ++k) a += hL[k0 + k] * Wh[(k0 + k) * 40 + j];
            wq[t][j] = a;
        }
        __syncthreads();
        if (tid < 40)
            outh[v * 40 + tid] = bh[tid] + wq[0][tid] + wq[1][tid]
                                         + wq[2][tid] + wq[3][tid];
    }
}

extern "C" void kernel_launch(void* const* d_in, const int* in_sizes, int n_in,
                              void* d_out, int out_size, void* d_ws, size_t ws_size,
                              hipStream_t stream) {
    const float* x   = (const float*)d_in[0];
    const int*   A   = (const int*)  d_in[1];
    const float* Wp1 = (const float*)d_in[2];
    const float* bp1 = (const float*)d_in[3];
    const float* Ws1 = (const float*)d_in[4];
    const float* bs1 = (const float*)d_in[5];
    const float* Wn1 = (const float*)d_in[6];
    const float* bn1 = (const float*)d_in[7];
    const float* Wp2 = (const float*)d_in[8];
    const float* bp2 = (const float*)d_in[9];
    const float* Ws2 = (const float*)d_in[10];
    const float* bs2 = (const float*)d_in[11];
    const float* Wn2 = (const float*)d_in[12];
    const float* bn2 = (const float*)d_in[13];
    const float* Wh  = (const float*)d_in[14];
    const float* bh  = (const float*)d_in[15];
    float* out = (float*)d_out;

    char* ws = (char*)d_ws;
    float* pooled1 = (float*)(ws);                  // 512 KB
    float* s1      = (float*)(ws + (512u << 10));   // 256 KB
    float* pooled2 = (float*)(ws + (768u << 10));   // 512 KB
    float* s2      = (float*)(ws + (1280u << 10));  // 256 KB
    int*   nbrG    = (int*)  (ws + (1536u << 10));  // 4 MB
    int*   cntG    = (int*)  (ws + (5632u << 10));  // 4 KB

    lin_build<<<NN / 4, 512, 0, stream>>>(x, Wp1, bp1, Ws1, bs1, A,
                                          pooled1, s1, nbrG, cntG);
    agg_kernel<0><<<NN, 256, 0, stream>>>(nbrG, cntG, pooled1, s1, Wn1, bn1,
                                          Wp2, bp2, Ws2, bs2,
                                          pooled2, s2, nullptr, nullptr, nullptr);
    agg_kernel<1><<<NN, 256, 0, stream>>>(nbrG, cntG, pooled2, s2, Wn2, bn2,
                                          nullptr, nullptr, nullptr, nullptr,
                                          nullptr, nullptr, Wh, bh, out);
}

// Round 15
// 28.500 us; speedup vs baseline: 1.4172x; 1.1124x over previous
//
#include <hip/hip_runtime.h>

#define NN 1024

// ---------- K1: first linear + neighbor-list build (A read ONCE) ----------
// 256 blocks x 512 threads, 4 nodes/block.
__global__ __launch_bounds__(512) void lin_build(
    const float* __restrict__ X, const float* __restrict__ Wp,
    const float* __restrict__ bp, const float* __restrict__ Ws,
    const float* __restrict__ bs, const int* __restrict__ A,
    float* __restrict__ pooled, float* __restrict__ sbuf,
    int* __restrict__ nbrG, int* __restrict__ cntG)
{
    __shared__ float xL[4][128];
    __shared__ float lp[2][4][192];
    __shared__ unsigned long long masksL[4][16];
    __shared__ int pfxL[4][16];

    const int tid  = threadIdx.x;
    const int lane = tid & 63;
    const int wv   = tid >> 6;       // wave 0..7
    const int v0   = blockIdx.x * 4;

    xL[tid >> 7][tid & 127] = X[v0 * 128 + tid];
    __syncthreads();

    if (tid < 384) {  // GEMV partials: 192 outputs x 2 k-halves, 4 rows/thread
        const int kh = (tid >= 192) ? 1 : 0;
        const int j = tid - kh * 192;
        const float* w; int ld;
        if (j < 128) { w = Wp + j;         ld = 128; }
        else         { w = Ws + (j - 128); ld = 64;  }
        const int k0 = kh * 64;
        float a0 = 0.f, a1 = 0.f, a2 = 0.f, a3 = 0.f;
        #pragma unroll 4
        for (int k = 0; k < 64; ++k) {
            const float wvv = w[(k0 + k) * ld];
            a0 += xL[0][k0 + k] * wvv;  a1 += xL[1][k0 + k] * wvv;
            a2 += xL[2][k0 + k] * wvv;  a3 += xL[3][k0 + k] * wvv;
        }
        lp[kh][0][j] = a0; lp[kh][1][j] = a1; lp[kh][2][j] = a2; lp[kh][3][j] = a3;
    }
    {   // A-scan: wave wv -> row (wv>>1), chunks (wv&1)*8..+8
        const int r = wv >> 1;
        const int* Arow = A + (v0 + r) * NN;
        #pragma unroll
        for (int c8 = 0; c8 < 8; ++c8) {
            const int c = (wv & 1) * 8 + c8;
            const unsigned long long m = __ballot(Arow[c * 64 + lane] != 0);
            if (lane == 0) masksL[r][c] = m;
        }
    }
    __syncthreads();

    if (tid < 4) {
        int off = 0;
        #pragma unroll
        for (int c = 0; c < 16; ++c) {
            pfxL[tid][c] = off;
            off += __popcll(masksL[tid][c]);
        }
        cntG[v0 + tid] = off;
    }
    if (tid < 192) {
        #pragma unroll
        for (int r = 0; r < 4; ++r) {
            const float t = lp[0][r][tid] + lp[1][r][tid];
            if (tid < 128) pooled[(v0 + r) * 128 + tid] = fmaxf(t + bp[tid], 0.f);
            else           sbuf[(v0 + r) * 64 + (tid - 128)] = t + bs[tid - 128];
        }
    }
    __syncthreads();

    {   // compaction scatter
        const int r = wv >> 1;
        #pragma unroll
        for (int c8 = 0; c8 < 8; ++c8) {
            const int c = (wv & 1) * 8 + c8;
            const unsigned long long m = masksL[r][c];
            if ((m >> lane) & 1ull) {
                const int pos = pfxL[r][c] + __popcll(m & ((1ull << lane) - 1ull));
                nbrG[(v0 + r) * NN + pos] = c * 64 + lane;
            }
        }
    }
}

// ---------- K2/K3: TWO nodes per block; weights reused for both ----------
// 512 blocks x 512 threads (2 blocks/CU, 16 waves/CU). Best measured config.
// MODE 0: writes pooled2 = relu(h@Wp2+bp2), s2 = h@Ws2+bs2
// MODE 1: Wp2:=Wh, bp2:=bh; writes outh = h@Wh+bh
template <int MODE>
__global__ __launch_bounds__(512) void agg_kernel(
    const int* __restrict__ nbrG, const int* __restrict__ cntG,
    const float* __restrict__ pooled, const float* __restrict__ sbuf,
    const float* __restrict__ Wn, const float* __restrict__ bn,
    const float* __restrict__ Wp2, const float* __restrict__ bp2,
    const float* __restrict__ Ws2, const float* __restrict__ bs2,
    float* __restrict__ out_pooled, float* __restrict__ out_s,
    float* __restrict__ outh)
{
    __shared__ int   nbr[2][NN];
    __shared__ float sL[2][64];
    __shared__ float part[4][128];
    __shared__ float aggL[2][128];
    __shared__ float wq[2][8][64];   // ksplit-8 partials (Wn, and head in MODE1)
    __shared__ float hL[2][128];
    __shared__ float lp2[2][2][192]; // MODE0 lin partials [kh][node][j]
    __shared__ float red[2][2];

    const int v0  = blockIdx.x * 2;
    const int tid = threadIdx.x;

    // front-end: counts + self-linear rows + both neighbor lists
    const int n0 = cntG[v0], n1 = cntG[v0 + 1];
    if (tid < 128) sL[tid >> 6][tid & 63] = sbuf[v0 * 64 + tid];
    for (int i = tid; i < n0; i += 512) nbr[0][i] = nbrG[v0 * NN + i];
    for (int i = tid; i < n1; i += 512) nbr[1][i] = nbrG[(v0 + 1) * NN + i];
    __syncthreads();

    // gather-max: slice s=tid>>7; node r=s>>1, offset o=s&1, stride 2, 8 accs
    {
        const int d = tid & 127, s = tid >> 7;
        const int r = s >> 1, o = s & 1;
        const int n = r ? n1 : n0;
        const int* nb = nbr[r];
        float a0=-1e30f,a1=-1e30f,a2=-1e30f,a3=-1e30f,
              a4=-1e30f,a5=-1e30f,a6=-1e30f,a7=-1e30f;
        int p = o;
        for (; p + 14 < n; p += 16) {
            a0 = fmaxf(a0, pooled[nb[p]      * 128 + d]);
            a1 = fmaxf(a1, pooled[nb[p + 2]  * 128 + d]);
            a2 = fmaxf(a2, pooled[nb[p + 4]  * 128 + d]);
            a3 = fmaxf(a3, pooled[nb[p + 6]  * 128 + d]);
            a4 = fmaxf(a4, pooled[nb[p + 8]  * 128 + d]);
            a5 = fmaxf(a5, pooled[nb[p + 10] * 128 + d]);
            a6 = fmaxf(a6, pooled[nb[p + 12] * 128 + d]);
            a7 = fmaxf(a7, pooled[nb[p + 14] * 128 + d]);
        }
        for (; p < n; p += 2) a0 = fmaxf(a0, pooled[nb[p] * 128 + d]);
        a0 = fmaxf(a0, a1); a2 = fmaxf(a2, a3);
        a4 = fmaxf(a4, a5); a6 = fmaxf(a6, a7);
        part[s][d] = fmaxf(fmaxf(a0, a2), fmaxf(a4, a6));
    }
    __syncthreads();
    if (tid < 256) {  // combine slices; isolated -> 0
        const int r = tid >> 7, d = tid & 127;
        const float m = fmaxf(part[2 * r][d], part[2 * r + 1][d]);
        aggL[r][d] = (m <= -5e29f) ? 0.f : m;
    }
    __syncthreads();

    // agg @ Wn: ksplit-8 x 64 outputs = 512 tasks, BOTH nodes per thread
    {
        const int t = tid >> 6, j = tid & 63, k0 = t * 16;
        float a0 = 0.f, a1 = 0.f;
        #pragma unroll
        for (int k = 0; k < 16; ++k) {
            const float w = Wn[(k0 + k) * 64 + j];
            a0 += aggL[0][k0 + k] * w;
            a1 += aggL[1][k0 + k] * w;
        }
        wq[0][t][j] = a0; wq[1][t][j] = a1;
    }
    __syncthreads();

    // concat + relu + L2 normalize (nodes on waves 0-1 / 2-3)
    float val = 0.f;
    {
        const int r = (tid >> 7) & 1, d = tid & 127;
        if (tid < 256) {
            if (d < 64) val = sL[r][d];
            else {
                const int j = d - 64;
                float acc = bn[j];
                #pragma unroll
                for (int t = 0; t < 8; ++t) acc += wq[r][t][j];
                val = acc;
            }
            val = fmaxf(val, 0.f);
        }
        float ss = val * val;
        #pragma unroll
        for (int off = 32; off >= 1; off >>= 1) ss += __shfl_xor(ss, off, 64);
        if (tid < 256 && (tid & 63) == 0) red[r][(tid >> 6) & 1] = ss;
    }
    __syncthreads();
    if (tid < 256) {
        const int r = tid >> 7, d = tid & 127;
        const float nrm = fmaxf(sqrtf(red[r][0] + red[r][1]), 1e-12f);
        hL[r][d] = val / nrm;
    }
    __syncthreads();

    if (MODE == 0) {
        // next-layer linears: 192 outputs x 2 k-halves, both nodes per thread
        if (tid < 384) {
            const int kh = (tid >= 192) ? 1 : 0;
            const int j  = tid - kh * 192;
            const float* w; int ld;
            if (j < 128) { w = Wp2 + j;         ld = 128; }
            else         { w = Ws2 + (j - 128); ld = 64;  }
            const int k0 = kh * 64;
            float a0 = 0.f, a1 = 0.f;
            #pragma unroll 4
            for (int k = 0; k < 64; ++k) {
                const float wv = w[(k0 + k) * ld];
                a0 += hL[0][k0 + k] * wv;
                a1 += hL[1][k0 + k] * wv;
            }
            lp2[kh][0][j] = a0; lp2[kh][1][j] = a1;
        }
        __syncthreads();
        if (tid < 192) {
            #pragma unroll
            for (int r = 0; r < 2; ++r) {
                const float t = lp2[0][r][tid] + lp2[1][r][tid];
                if (tid < 128) out_pooled[(v0 + r) * 128 + tid] = fmaxf(t + bp2[tid], 0.f);
                else           out_s[(v0 + r) * 64 + (tid - 128)] = t + bs2[tid - 128];
            }
        }
    } else {
        // head: ksplit-8 x 40 outputs = 320 tasks, both nodes per thread
        if (tid < 320) {
            const int t = tid / 40, j = tid - t * 40;
            const int k0 = t * 16;
            float a0 = 0.f, a1 = 0.f;
            #pragma unroll
            for (int k = 0; k < 16; ++k) {
                const float wv = Wp2[(k0 + k) * 40 + j];  // Wp2 := Wh
                a0 += hL[0][k0 + k] * wv;
                a1 += hL[1][k0 + k] * wv;
            }
            wq[0][t][j] = a0; wq[1][t][j] = a1;
        }
        __syncthreads();
        if (tid < 80) {
            const int r = tid / 40, j = tid - r * 40;
            float acc = bp2[j];  // bh
            #pragma unroll
            for (int t = 0; t < 8; ++t) acc += wq[r][t][j];
            outh[(v0 + r) * 40 + j] = acc;
        }
    }
}

extern "C" void kernel_launch(void* const* d_in, const int* in_sizes, int n_in,
                              void* d_out, int out_size, void* d_ws, size_t ws_size,
                              hipStream_t stream) {
    const float* x   = (const float*)d_in[0];
    const int*   A   = (const int*)  d_in[1];
    const float* Wp1 = (const float*)d_in[2];
    const float* bp1 = (const float*)d_in[3];
    const float* Ws1 = (const float*)d_in[4];
    const float* bs1 = (const float*)d_in[5];
    const float* Wn1 = (const float*)d_in[6];
    const float* bn1 = (const float*)d_in[7];
    const float* Wp2 = (const float*)d_in[8];
    const float* bp2 = (const float*)d_in[9];
    const float* Ws2 = (const float*)d_in[10];
    const float* bs2 = (const float*)d_in[11];
    const float* Wn2 = (const float*)d_in[12];
    const float* bn2 = (const float*)d_in[13];
    const float* Wh  = (const float*)d_in[14];
    const float* bh  = (const float*)d_in[15];
    float* out = (float*)d_out;

    char* ws = (char*)d_ws;
    float* pooled1 = (float*)(ws);                  // 512 KB
    float* s1      = (float*)(ws + (512u << 10));   // 256 KB
    float* pooled2 = (float*)(ws + (768u << 10));   // 512 KB
    float* s2      = (float*)(ws + (1280u << 10));  // 256 KB
    int*   nbrG    = (int*)  (ws + (1536u << 10));  // 4 MB
    int*   cntG    = (int*)  (ws + (5632u << 10));  // 4 KB

    lin_build<<<NN / 4, 512, 0, stream>>>(x, Wp1, bp1, Ws1, bs1, A,
                                          pooled1, s1, nbrG, cntG);
    agg_kernel<0><<<NN / 2, 512, 0, stream>>>(nbrG, cntG, pooled1, s1, Wn1, bn1,
                                              Wp2, bp2, Ws2, bs2,
                                              pooled2, s2, nullptr);
    agg_kernel<1><<<NN / 2, 512, 0, stream>>>(nbrG, cntG, pooled2, s2, Wn2, bn2,
                                              Wh, bh, nullptr, nullptr,
                                              nullptr, nullptr, out);
}